// Round 14
// baseline (271.239 us; speedup 1.0000x reference)
//
#include <hip/hip_runtime.h>

#define BATCH 8
#define SEQ   2048
#define DIM   768
#define VOCAB 50257
#define NTOK  (BATCH * SEQ)        // 16384
#define NBUCKET 3142               // ceil(VOCAB/16)
#define NGROUP  393                // 8 buckets = 128 cols per group
#define NCHUNK  24                 // 768 / 32 rows per chunk
#define OFF_BASE NTOK              // ws[NTOK .. NTOK+4096): bucket start offsets
#define SORT_THREADS 1024
#define PCOLS 128                  // panel columns (vocab dim)
#define PROWS 32                   // panel rows (emb dim)
#define TCAP  128                  // token-list LDS capacity (lambda~42, max<<128)

typedef float f32x4 __attribute__((ext_vector_type(4)));

// ---------------------------------------------------------------------------
// Kernel 1: counting-sort the 16384 (token, flat_pos) pairs by bucket (t>>4).
// Dumps exclusive bucket-start offsets to ws[OFF_BASE..OFF_BASE+4096).
// ws[j] = (t << 14) | flat_pos for the sorted stream. (Unchanged.)
// ---------------------------------------------------------------------------
__global__ __launch_bounds__(SORT_THREADS) void sort_tokens_kernel(
    const int* __restrict__ tokens, unsigned* __restrict__ ws)
{
    __shared__ unsigned cnt[4096];
    __shared__ unsigned wsum[16];
    const int tid = threadIdx.x;

    for (int j = tid; j < 4096; j += SORT_THREADS) cnt[j] = 0;
    __syncthreads();

    for (int i = tid; i < NTOK; i += SORT_THREADS) {
        int t = tokens[i];
        atomicAdd(&cnt[t >> 4], 1u);
    }
    __syncthreads();

    unsigned c0 = cnt[4*tid+0], c1 = cnt[4*tid+1], c2 = cnt[4*tid+2], c3 = cnt[4*tid+3];
    unsigned tsum = c0 + c1 + c2 + c3;
    unsigned x = tsum;
    for (int off = 1; off < 64; off <<= 1) {
        unsigned y = __shfl_up(x, off, 64);
        if ((tid & 63) >= off) x += y;
    }
    if ((tid & 63) == 63) wsum[tid >> 6] = x;
    __syncthreads();
    if (tid < 16) {
        unsigned w = wsum[tid];
        for (int off = 1; off < 16; off <<= 1) {
            unsigned y = __shfl_up(w, off, 64);
            if (tid >= off) w += y;
        }
        wsum[tid] = w;
    }
    __syncthreads();
    unsigned wavebase = (tid >= 64) ? wsum[(tid >> 6) - 1] : 0u;
    unsigned excl = wavebase + x - tsum;
    cnt[4*tid+0] = excl;
    cnt[4*tid+1] = excl + c0;
    cnt[4*tid+2] = excl + c0 + c1;
    cnt[4*tid+3] = excl + c0 + c1 + c2;
    __syncthreads();

    for (int j = tid; j < 4096; j += SORT_THREADS) ws[OFF_BASE + j] = cnt[j];
    __syncthreads();

    for (int i = tid; i < NTOK; i += SORT_THREADS) {
        int t = tokens[i];
        unsigned p = atomicAdd(&cnt[t >> 4], 1u);
        ws[p] = ((unsigned)t << 14) | (unsigned)i;
    }
}

// ---------------------------------------------------------------------------
// Kernel 2: small-panel kernel. Block b = (group G = b/24, row-chunk rc = b%24).
// Group G: vocab cols [128G, 128G+128); chunk rc: emb rows [32rc, 32rc+32).
// 128 threads, 16 KB slab -> ~9 blocks/CU resident (vs 3 in R8/R10): 3x the
// outstanding staging loads per CU + inter-block stage/emit overlap.
//
// LDS: row-major slab[row][col ^ ((row>>2 & 7)<<2)] — b128 writes contiguous
// per row; emission scalar col-reads spread over 8 banks.
// Emission: u = tok*8 + lp (power-of-2, no div); 8 tokens in flight per wave;
// token list preloaded in LDS.
// ---------------------------------------------------------------------------
__global__ __launch_bounds__(128) void emb_panel_kernel(
    const unsigned* __restrict__ ws,
    const float*    __restrict__ W_emb,
    const float*    __restrict__ W_pos,
    float*          __restrict__ out)
{
    __shared__ float slab[PROWS * PCOLS];   // 16 KiB
    __shared__ unsigned tlist[TCAP];

    const int b  = blockIdx.x;
    const int G  = b / NCHUNK;              // group 0..392
    const int rc = b - G * NCHUNK;          // row chunk 0..23
    const unsigned start = ws[OFF_BASE + G * 8];
    const unsigned end   = ws[OFF_BASE + G * 8 + 8];
    if (start == end) return;

    const int cbase = G * PCOLS;
    const int rbase = rc * PROWS;
    const int tid   = threadIdx.x;
    const int ntok  = (int)(end - start);

    // ---- preload token list (tiny, overlaps with staging issue)
    if (ntok <= TCAP) {
        for (int j = tid; j < ntok; j += 128) tlist[j] = ws[start + j];
    }

    // ---- stage: 8 x f32x4 per thread; all loads issued, then LDS writes
    f32x4 v[8];
    #pragma unroll
    for (int it = 0; it < 8; ++it) {
        const int fo  = it * 512 + tid * 4;
        const int row = fo >> 7;            // 0..31
        const int col = fo & 127;
        const int gcol = cbase + col;
        const float* src = W_emb + (size_t)(rbase + row) * VOCAB + gcol;
        if (gcol + 4 <= VOCAB) {
            v[it] = *reinterpret_cast<const f32x4*>(src);
        } else {
            f32x4 tmp = {0.f, 0.f, 0.f, 0.f};
            #pragma unroll
            for (int k = 0; k < 4; ++k)
                if (gcol + k < VOCAB) tmp[k] = src[k];
            v[it] = tmp;
        }
    }
    #pragma unroll
    for (int it = 0; it < 8; ++it) {
        const int fo  = it * 512 + tid * 4;
        const int row = fo >> 7;
        const int col = fo & 127;
        const int colx = col ^ (((row >> 2) & 7) << 2);
        *reinterpret_cast<f32x4*>(&slab[row * PCOLS + colx]) = v[it];
    }
    __syncthreads();

    // ---- emission: u = tok*8 + lp; thread handles rows d0..d0+3 of token tok
    const bool cached = (ntok <= TCAP);
    const int U = ntok * 8;
    for (int u = tid; u < U; u += 128) {
        const int tok = u >> 3;
        const int lp  = u & 7;
        const unsigned packed = cached ? tlist[tok] : ws[start + tok];
        const int t = (int)(packed >> 14);
        const int i = (int)(packed & 16383u);   // flat b*SEQ+s
        const int s = i & (SEQ - 1);
        const int j = t - cbase;                // 0..127
        const int d0 = lp * 4;                  // 0..28

        float e[4];
        #pragma unroll
        for (int k = 0; k < 4; ++k) {
            const int row = d0 + k;
            e[k] = slab[row * PCOLS + (j ^ (((row >> 2) & 7) << 2))];
        }
        const f32x4 p = *reinterpret_cast<const f32x4*>(
            W_pos + (size_t)s * DIM + rbase + d0);
        f32x4 rr;
        rr.x = e[0] + p.x; rr.y = e[1] + p.y; rr.z = e[2] + p.z; rr.w = e[3] + p.w;
        __builtin_nontemporal_store(rr,
            reinterpret_cast<f32x4*>(out + (size_t)i * DIM + rbase + d0));
    }
}

extern "C" void kernel_launch(void* const* d_in, const int* in_sizes, int n_in,
                              void* d_out, int out_size, void* d_ws, size_t ws_size,
                              hipStream_t stream) {
    const int*   tokens = (const int*)  d_in[0];
    const float* W_emb  = (const float*)d_in[1];
    const float* W_pos  = (const float*)d_in[2];
    float*       out    = (float*)d_out;
    unsigned*    ws     = (unsigned*)d_ws;   // (16384 + 4096) * 4 B = 80 KiB

    sort_tokens_kernel<<<dim3(1), dim3(SORT_THREADS), 0, stream>>>(tokens, ws);
    emb_panel_kernel<<<dim3(NGROUP * NCHUNK), dim3(128), 0, stream>>>(ws, W_emb, W_pos, out);
}